// Round 13
// baseline (307.787 us; speedup 1.0000x reference)
//
#include <hip/hip_runtime.h>
#include <hip/hip_bf16.h>
#include <stdint.h>

typedef unsigned int uint32;
typedef unsigned short ushort16;

typedef __attribute__((ext_vector_type(8))) short short8;
typedef __attribute__((ext_vector_type(4))) float f32x4;

#define N_NODES 50000
#define N_EDGES 800000
#define FD      128
#define NGRAPH  64
#define MTILES  3125   // N_NODES / 16 exactly
#define NBK     196    // coarse buckets = ceil(50000/256)
#define GB      391    // sort blocks (2048 edges each)
#define GB2     782    // gemm blocks (4 m-tiles each, 1 per wave)
#define PCH     32     // pool chunks per graph
#define SBK     16     // scan split blocks
#define KCH2    25     // ceil(391/16)
#define SCAP    6144   // LDS staging capacity for bucket sort (u16)

__device__ __forceinline__ float bf2f(ushort16 u){
  union { uint32 i; float f; } v; v.i = ((uint32)u) << 16; return v.f;
}
__device__ __forceinline__ float bf2f_lo(uint32 w){ union{uint32 i;float f;}v; v.i = w << 16; return v.f; }
__device__ __forceinline__ float bf2f_hi(uint32 w){ union{uint32 i;float f;}v; v.i = w & 0xffff0000u; return v.f; }
__device__ __forceinline__ ushort16 f2bf(float f){
  uint32 u = __float_as_uint(f);
  u += 0x7fffu + ((u >> 16) & 1u);   // round-to-nearest-even
  return (ushort16)(u >> 16);
}

__device__ __forceinline__ int ld_idx(const void* p, uint32 is64, size_t i){
  return is64 ? (int)((const long long*)p)[i] : ((const int*)p)[i];
}
__device__ __forceinline__ float ld_f(const void* p, uint32 isf32, int i){
  return isf32 ? ((const float*)p)[i] : bf2f(((const ushort16*)p)[i]);
}

// ---- inline dtype detection (per-wave, 2 broadcast loads + 2 ballots) ------
__device__ __forceinline__ void get_flags(const uint32* __restrict__ xw,
    const uint32* __restrict__ eiw, uint32& isf32, uint32& is64)
{
  int l = threadIdx.x & 63;
  uint32 w = xw[l];
  uint32 e8 = (w >> 7) & 0xFFu;              // exponent of the LOW bf16 half
  bool bf_like = (e8 >= 0x70u && e8 <= 0x82u);
  unsigned long long m = __ballot(bf_like);
  isf32 = (__popcll(m) < 32) ? 1u : 0u;
  uint32 hi = (l < 8) ? eiw[2*l + 1] : 1u;   // int64 high words are 0
  unsigned long long z = __ballot(hi == 0u);
  is64 = ((z & 0xFFull) == 0xFFull) ? 1u : 0u;
}

// ---------------- CSR build + gseg + prep, one grid -------------------------

__global__ __launch_bounds__(256) void pack_gseg_prep_kernel(
    const void* __restrict__ ei, const void* __restrict__ batch,
    const void* __restrict__ X,
    const void* __restrict__ WL1, const void* __restrict__ WR1,
    const void* __restrict__ WL2, const void* __restrict__ WR2,
    uint32* __restrict__ pack0, uint32* __restrict__ hist, uint32* __restrict__ gstart,
    ushort16* __restrict__ xb, short* __restrict__ wfrag)
{
  uint32 isf32, is64;
  get_flags((const uint32*)X, (const uint32*)ei, isf32, is64);
  int tid = threadIdx.x;
  if (blockIdx.x < GB){
    __shared__ uint32 h[256];
    h[tid] = 0u;
    __syncthreads();
    int base = blockIdx.x*2048;
    for (int r = 0; r < 8; ++r){
      int i = base + r*256 + tid;
      if (i < N_EDGES){
        uint32 s = (uint32)ld_idx(ei, is64, i);
        uint32 d = (uint32)ld_idx(ei, is64, (size_t)N_EDGES + i);
        pack0[i] = (d << 16) | s;
        atomicAdd(&h[d >> 8], 1u);             // LDS atomic
      }
    }
    __syncthreads();
    hist[blockIdx.x*256 + tid] = h[tid];
  } else if (blockIdx.x < GB + 196){
    int t = (blockIdx.x - GB)*256 + tid;
    if (t >= N_NODES) return;
    int b1 = ld_idx(batch, is64, t);
    int b0 = (t == 0) ? -1 : ld_idx(batch, is64, t - 1);
    for (int g = b0 + 1; g <= b1; ++g) gstart[g] = (uint32)t;
    if (t == N_NODES - 1)
      for (int g = b1 + 1; g <= NGRAPH; ++g) gstart[g] = (uint32)N_NODES;
  } else if (blockIdx.x < GB + 196 + 3125){
    if (!isf32) return;                        // bf16 input used in place
    size_t e = ((size_t)(blockIdx.x - GB - 196)*256 + tid)*8;
    const float* p = (const float*)X + e;
    float4 u = *(const float4*)p;
    float4 v = *(const float4*)(p + 4);
    uint4 o;
    o.x = (uint32)f2bf(u.x) | ((uint32)f2bf(u.y) << 16);
    o.y = (uint32)f2bf(u.z) | ((uint32)f2bf(u.w) << 16);
    o.z = (uint32)f2bf(v.x) | ((uint32)f2bf(v.y) << 16);
    o.w = (uint32)f2bf(v.z) | ((uint32)f2bf(v.w) << 16);
    *(uint4*)(xb + e) = o;
  } else {
    int t = (blockIdx.x - GB - 196 - 3125)*256 + tid;   // 65536 total
    int layer = t >> 15;
    int r = t & 32767;
    int k = r >> 7, n = r & 127;
    const void* w = layer ? (k < 128 ? WL2 : WR2) : (k < 128 ? WL1 : WR1);
    int kk = k & 127;
    float wv = ld_f(w, isf32, kk*128 + n);
    int off = (((k >> 5)*8 + (n >> 4))*64 + (n & 15) + 16*((kk >> 3) & 3))*8 + (kk & 7);
    wfrag[layer*32768 + off] = (short)f2bf(wv);
  }
}

// ---------------- scan of hist, 3-phase (16 CUs instead of 1) ---------------

__global__ __launch_bounds__(256) void scan_part_kernel(const uint32* __restrict__ hist,
    uint32* __restrict__ part)
{
  int b = threadIdx.x, p = blockIdx.x;
  int k0 = p*KCH2, k1 = (k0 + KCH2 < GB) ? k0 + KCH2 : GB;
  uint32 sum = 0;
  for (int k = k0; k < k1; ++k) sum += hist[k*256 + b];
  part[p*256 + b] = sum;
}

__global__ __launch_bounds__(256) void scan_mid_kernel(const uint32* __restrict__ part,
    uint32* __restrict__ pbase, uint32* __restrict__ bbase)
{
  __shared__ uint32 lds[256];
  int b = threadIdx.x;
  uint32 tot = 0;
#pragma unroll
  for (int p = 0; p < SBK; ++p) tot += part[p*256 + b];
  uint32 x = tot;
  lds[b] = x; __syncthreads();
  for (int o = 1; o < 256; o <<= 1){
    uint32 y = (b >= o) ? lds[b - o] : 0u;
    __syncthreads();
    x += y; lds[b] = x;
    __syncthreads();
  }
  uint32 base = x - tot;                      // exclusive bucket base
  if (b <= NBK) bbase[b] = (b < NBK) ? base : (uint32)N_EDGES;
  uint32 run = base;
#pragma unroll
  for (int p = 0; p < SBK; ++p){
    pbase[p*256 + b] = run;
    run += part[p*256 + b];
  }
}

__global__ __launch_bounds__(256) void scan_off_kernel(const uint32* __restrict__ hist,
    const uint32* __restrict__ pbase, uint32* __restrict__ off)
{
  int b = threadIdx.x, p = blockIdx.x;
  int k0 = p*KCH2, k1 = (k0 + KCH2 < GB) ? k0 + KCH2 : GB;
  uint32 run = pbase[p*256 + b];
  for (int k = k0; k < k1; ++k){
    off[k*256 + b] = run;
    run += hist[k*256 + b];
  }
}

__global__ __launch_bounds__(256) void scatter_kernel(const uint32* __restrict__ pack0,
    const uint32* __restrict__ off, uint32* __restrict__ pack1)
{
  __shared__ uint32 cur[256];
  int tid = threadIdx.x;
  cur[tid] = off[blockIdx.x*256 + tid];
  __syncthreads();
  int base = blockIdx.x*2048;
  for (int r = 0; r < 8; ++r){
    int i = base + r*256 + tid;
    if (i < N_EDGES){
      uint32 p = pack0[i];
      uint32 pos = atomicAdd(&cur[p >> 24], 1u);   // LDS atomic
      pack1[pos] = p;
    }
  }
}

// CSR for the bucket + per-node neighbor lists SORTED by src (LDS staging +
// insertion sort). Sorting is a pure L2-locality optimization: all concurrent
// agg threads then walk src-space in lockstep (working window << 4MB L2).
__global__ __launch_bounds__(256) void bucket_csr_kernel(const uint32* __restrict__ pack1,
    const uint32* __restrict__ bbase, uint32* __restrict__ rowstart,
    uint32* __restrict__ deg, ushort16* __restrict__ colidx)
{
  __shared__ uint32 cnt[256];
  __shared__ uint32 lds[256];
  __shared__ uint32 cur[256];
  __shared__ ushort16 sco[SCAP];                   // 12 KB staging
  int tid = threadIdx.x;
  int bk = blockIdx.x;
  uint32 e0 = bbase[bk], e1 = bbase[bk + 1];
  uint32 ecnt = e1 - e0;
  bool fits = (ecnt <= SCAP);
  cnt[tid] = 0u;
  __syncthreads();
  for (uint32 i = e0 + tid; i < e1; i += 256)
    atomicAdd(&cnt[(pack1[i] >> 16) & 255u], 1u);  // LDS atomic
  __syncthreads();
  uint32 v = cnt[tid];
  uint32 x = v;
  lds[tid] = x; __syncthreads();
  for (int o = 1; o < 256; o <<= 1){
    uint32 y = (tid >= o) ? lds[tid - o] : 0u;
    __syncthreads();
    x += y; lds[tid] = x;
    __syncthreads();
  }
  uint32 start = e0 + x - v;
  int node = bk*256 + tid;
  if (node < N_NODES){ rowstart[node] = start; deg[node] = v; }
  cur[tid] = start;
  __syncthreads();
  if (fits){
    for (uint32 i = e0 + tid; i < e1; i += 256){
      uint32 p = pack1[i];
      uint32 pos = atomicAdd(&cur[(p >> 16) & 255u], 1u);  // LDS atomic
      sco[pos - e0] = (ushort16)(p & 0xFFFFu);
    }
    __syncthreads();
    // per-node insertion sort (d ~ 16) on the LDS segment
    {
      uint32 s = start - e0;
      for (uint32 j = 1; j < v; ++j){
        ushort16 key = sco[s + j];
        int k = (int)j - 1;
        while (k >= 0 && sco[s + k] > key){ sco[s + k + 1] = sco[s + k]; --k; }
        sco[s + k + 1] = key;
      }
    }
    __syncthreads();
    for (uint32 i = e0 + tid; i < e1; i += 256)    // coalesced write-out
      colidx[i] = sco[i - e0];
  } else {
    for (uint32 i = e0 + tid; i < e1; i += 256){   // fallback: unsorted
      uint32 p = pack1[i];
      uint32 pos = atomicAdd(&cur[(p >> 16) & 255u], 1u);
      colidx[pos] = (ushort16)(p & 0xFFFFu);
    }
  }
}

// ---------------- mean aggregation (pull, CSR); APPLY fuses BN+ReLU --------
// 16 lanes per node (coalesced 256B rows), unroll-8 gathers in flight.
// Neighbor lists are src-sorted -> concurrent threads stream src-space.

__device__ __forceinline__ void acc8(float* a, uint4 v, const float* s0, const float* h0, int APPLY){
  float f[8];
  f[0] = bf2f_lo(v.x); f[1] = bf2f_hi(v.x);
  f[2] = bf2f_lo(v.y); f[3] = bf2f_hi(v.y);
  f[4] = bf2f_lo(v.z); f[5] = bf2f_hi(v.z);
  f[6] = bf2f_lo(v.w); f[7] = bf2f_hi(v.w);
#pragma unroll
  for (int j = 0; j < 8; ++j)
    a[j] += APPLY ? fmaxf(f[j]*s0[j] + h0[j], 0.f) : f[j];
}

template<int APPLY>
__global__ __launch_bounds__(256) void agg_kernel(const ushort16* __restrict__ Xd,
    const void* __restrict__ Xraw, const void* __restrict__ eiraw,
    const uint32* __restrict__ rowstart, const uint32* __restrict__ deg,
    const ushort16* __restrict__ colidx,
    const float* __restrict__ sc, const float* __restrict__ sh,
    ushort16* __restrict__ out)
{
  uint32 isf32, is64;
  get_flags((const uint32*)Xraw, (const uint32*)eiraw, isf32, is64);
  const ushort16* X = (APPLY == 0 && !isf32) ? (const ushort16*)Xraw : Xd;
  int t = blockIdx.x*256 + threadIdx.x;
  int node = t >> 4;
  int l = t & 15;
  uint32 st = rowstart[node];
  uint32 d  = deg[node];
  float s0[8], h0[8];
#pragma unroll
  for (int j = 0; j < 8; ++j){
    s0[j] = APPLY ? sc[l*8 + j] : 0.f;
    h0[j] = APPLY ? sh[l*8 + j] : 0.f;
  }
  float a[8];
#pragma unroll
  for (int j = 0; j < 8; ++j) a[j] = 0.f;
  const ushort16* Xl = X + l*8;
  uint32 i = 0;
  for (; i < d && ((st + i) & 3u); ++i){
    uint32 c = colidx[st + i];
    acc8(a, *(const uint4*)(Xl + (size_t)c*FD), s0, h0, APPLY);
  }
  for (; i + 8 <= d; i += 8){
    uint2 cA = *(const uint2*)(colidx + st + i);
    uint2 cB = *(const uint2*)(colidx + st + i + 4);
    uint4 v0 = *(const uint4*)(Xl + (size_t)(cA.x & 0xFFFFu)*FD);
    uint4 v1 = *(const uint4*)(Xl + (size_t)(cA.x >> 16)*FD);
    uint4 v2 = *(const uint4*)(Xl + (size_t)(cA.y & 0xFFFFu)*FD);
    uint4 v3 = *(const uint4*)(Xl + (size_t)(cA.y >> 16)*FD);
    uint4 v4 = *(const uint4*)(Xl + (size_t)(cB.x & 0xFFFFu)*FD);
    uint4 v5 = *(const uint4*)(Xl + (size_t)(cB.x >> 16)*FD);
    uint4 v6 = *(const uint4*)(Xl + (size_t)(cB.y & 0xFFFFu)*FD);
    uint4 v7 = *(const uint4*)(Xl + (size_t)(cB.y >> 16)*FD);
    acc8(a, v0, s0, h0, APPLY); acc8(a, v1, s0, h0, APPLY);
    acc8(a, v2, s0, h0, APPLY); acc8(a, v3, s0, h0, APPLY);
    acc8(a, v4, s0, h0, APPLY); acc8(a, v5, s0, h0, APPLY);
    acc8(a, v6, s0, h0, APPLY); acc8(a, v7, s0, h0, APPLY);
  }
  for (; i + 4 <= d; i += 4){
    uint2 cA = *(const uint2*)(colidx + st + i);
    uint4 v0 = *(const uint4*)(Xl + (size_t)(cA.x & 0xFFFFu)*FD);
    uint4 v1 = *(const uint4*)(Xl + (size_t)(cA.x >> 16)*FD);
    uint4 v2 = *(const uint4*)(Xl + (size_t)(cA.y & 0xFFFFu)*FD);
    uint4 v3 = *(const uint4*)(Xl + (size_t)(cA.y >> 16)*FD);
    acc8(a, v0, s0, h0, APPLY); acc8(a, v1, s0, h0, APPLY);
    acc8(a, v2, s0, h0, APPLY); acc8(a, v3, s0, h0, APPLY);
  }
  for (; i < d; ++i){
    uint32 c = colidx[st + i];
    acc8(a, *(const uint4*)(Xl + (size_t)c*FD), s0, h0, APPLY);
  }
  float inv = 1.f / fmaxf((float)d, 1.f);
  uint4 o;
  o.x = (uint32)f2bf(a[0]*inv) | ((uint32)f2bf(a[1]*inv) << 16);
  o.y = (uint32)f2bf(a[2]*inv) | ((uint32)f2bf(a[3]*inv) << 16);
  o.z = (uint32)f2bf(a[4]*inv) | ((uint32)f2bf(a[5]*inv) << 16);
  o.w = (uint32)f2bf(a[6]*inv) | ((uint32)f2bf(a[7]*inv) << 16);
  *(uint4*)(out + (size_t)node*FD + l*8) = o;
}

// ---------------- GEMM + bias + BN-stat partials (1 m-tile per wave) --------

__device__ __forceinline__ short8 affine_relu8(short8 a, const float* sc, const float* sh, int koff){
  short8 r;
#pragma unroll
  for (int j = 0; j < 8; ++j){
    float v = bf2f((ushort16)a[j]) * sc[koff + j] + sh[koff + j];
    r[j] = (short)f2bf(fmaxf(v, 0.f));
  }
  return r;
}

template<int APPLY>
__global__ __launch_bounds__(256) void gemm_bn_kernel(
    const ushort16* __restrict__ A0, const ushort16* __restrict__ A1d,
    const void* __restrict__ A1raw, const void* __restrict__ eiraw,
    const short* __restrict__ wfrag, const void* __restrict__ bias,
    const float* __restrict__ sc, const float* __restrict__ sh,
    const void* __restrict__ Xraw,
    ushort16* __restrict__ hpre, float* __restrict__ bnpart)
{
  __shared__ float red[256];
  uint32 isf32, is64;
  get_flags((const uint32*)Xraw, (const uint32*)eiraw, isf32, is64);
  const ushort16* A1 = (A1raw && !isf32) ? (const ushort16*)A1raw : A1d;
  int tid = threadIdx.x;
  red[tid] = 0.f;
  int wave = tid >> 6, lane = tid & 63, lq = lane >> 4, lm = lane & 15;
  int mt = blockIdx.x*4 + wave;
  bool valid = mt < MTILES;
  size_t m0 = (size_t)((valid ? mt : 0)*16 + lm);
  f32x4 acc[8];
#pragma unroll
  for (int i = 0; i < 8; ++i) acc[i] = (f32x4){0.f,0.f,0.f,0.f};

#pragma unroll
  for (int ks = 0; ks < 8; ++ks){
    int koff = (ks & 3)*32 + lq*8;
    const short* srcp = (const short*)(ks < 4 ? A0 : A1);
    short8 a = *(const short8*)(srcp + m0*FD + koff);
    if (APPLY && ks >= 4) a = affine_relu8(a, sc, sh, koff);
#pragma unroll
    for (int nt = 0; nt < 8; ++nt){
      short8 b = *(const short8*)&wfrag[((ks*8 + nt)*64 + lane)*8];
      acc[nt] = __builtin_amdgcn_mfma_f32_16x16x32_bf16(a, b, acc[nt], 0, 0, 0);
    }
  }

  __syncthreads();                              // red[] zero-init visible
#pragma unroll
  for (int nt = 0; nt < 8; ++nt){
    int colc = nt*16 + lm;                      // C/D: col = lane&15
    float bb = ld_f(bias, isf32, colc);
    float s = 0.f, s2 = 0.f;
    if (valid){
      size_t nb = (size_t)mt*16 + lq*4;         // C/D: row = quad*4 + reg
#pragma unroll
      for (int r = 0; r < 4; ++r){
        float val = acc[nt][r] + bb;
        hpre[(nb + r)*FD + colc] = f2bf(val);
        s += val; s2 += val*val;
      }
    }
    s  += __shfl_xor(s, 16);  s  += __shfl_xor(s, 32);
    s2 += __shfl_xor(s2, 16); s2 += __shfl_xor(s2, 32);
    if (lq == 0){
      atomicAdd(&red[colc], s);                 // LDS atomic
      atomicAdd(&red[128 + colc], s2);
    }
  }
  __syncthreads();
  bnpart[blockIdx.x*256 + tid] = red[tid];
}

// ---------------- BN finalize (16 blocks, shfl reduce) ----------------------

__global__ __launch_bounds__(256) void bn_final_kernel(const float* __restrict__ bnpart,
    const void* __restrict__ gamma, const void* __restrict__ beta,
    const void* __restrict__ Xraw, const void* __restrict__ eiraw,
    float* __restrict__ scale, float* __restrict__ shift)
{
  uint32 isf32, is64;
  get_flags((const uint32*)Xraw, (const uint32*)eiraw, isf32, is64);
  int tid = threadIdx.x;
  int f = blockIdx.x*8 + (tid >> 5);
  int l = tid & 31;
  float s = 0.f, q = 0.f;
  for (int b = l; b < GB2; b += 32){
    s += bnpart[b*256 + f];
    q += bnpart[b*256 + 128 + f];
  }
#pragma unroll
  for (int m = 16; m >= 1; m >>= 1){
    s += __shfl_xor(s, m);
    q += __shfl_xor(q, m);
  }
  if (l == 0){
    const float invN = 1.0f / (float)N_NODES;
    float mu  = s * invN;
    float var = q * invN - mu*mu;
    float scv = ld_f(gamma, isf32, f) * rsqrtf(var + 1e-5f);
    scale[f] = scv;
    shift[f] = ld_f(beta, isf32, f) - mu * scv;
  }
}

// ---------------- pool (BN2 + ReLU fused), high-occupancy -------------------

__global__ __launch_bounds__(256) void pool_partial_kernel(const ushort16* __restrict__ hp,
    const float* __restrict__ scale, const float* __restrict__ shift,
    const uint32* __restrict__ gstart, float* __restrict__ pool_part)
{
  __shared__ float wred[4*16*8];                 // 2 KB
  int tid = threadIdx.x;
  int g = blockIdx.x >> 5, chunk = blockIdx.x & 31;
  int slot = tid >> 4, l = tid & 15;
  int wave = tid >> 6, lane = tid & 63;
  uint32 st = gstart[g], cnt = gstart[g+1] - st;
  uint32 per = (cnt + PCH - 1) >> 5;
  uint32 b0 = st + chunk*per;
  uint32 b1 = b0 + per;
  uint32 e1 = st + cnt;
  if (b1 > e1) b1 = e1;
  float s0[8], h0[8], a[8];
#pragma unroll
  for (int j = 0; j < 8; ++j){ s0[j] = scale[l*8 + j]; h0[j] = shift[l*8 + j]; a[j] = 0.f; }
  for (uint32 n = b0 + slot; n < b1; n += 16){
    const uint4 v = *(const uint4*)(hp + (size_t)n*FD + l*8);
    float f[8];
    f[0] = bf2f_lo(v.x); f[1] = bf2f_hi(v.x);
    f[2] = bf2f_lo(v.y); f[3] = bf2f_hi(v.y);
    f[4] = bf2f_lo(v.z); f[5] = bf2f_hi(v.z);
    f[6] = bf2f_lo(v.w); f[7] = bf2f_hi(v.w);
#pragma unroll
    for (int j = 0; j < 8; ++j) a[j] += fmaxf(f[j]*s0[j] + h0[j], 0.f);
  }
#pragma unroll
  for (int j = 0; j < 8; ++j){
    a[j] += __shfl_xor(a[j], 16);
    a[j] += __shfl_xor(a[j], 32);
  }
  if (lane < 16){
#pragma unroll
    for (int j = 0; j < 8; ++j) wred[(wave*16 + lane)*8 + j] = a[j];
  }
  __syncthreads();
  if (tid < 16){
    float r[8];
#pragma unroll
    for (int j = 0; j < 8; ++j)
      r[j] = wred[(0*16 + tid)*8 + j] + wred[(1*16 + tid)*8 + j]
           + wred[(2*16 + tid)*8 + j] + wred[(3*16 + tid)*8 + j];
    float* dst = pool_part + (size_t)blockIdx.x*FD + tid*8;
#pragma unroll
    for (int j = 0; j < 8; ++j) dst[j] = r[j];
  }
}

__global__ void pool_final_kernel(const float* __restrict__ pool_part,
    const uint32* __restrict__ gstart, const void* __restrict__ Xraw,
    const void* __restrict__ eiraw, void* __restrict__ out)
{
  uint32 isf32, is64;
  get_flags((const uint32*)Xraw, (const uint32*)eiraw, isf32, is64);
  int t = blockIdx.x*256 + threadIdx.x;          // t < 8192
  int g = t >> 7, f = t & 127;
  float c = fmaxf((float)(gstart[g+1] - gstart[g]), 1.f);
  float v = 0.f;
#pragma unroll 8
  for (int ch = 0; ch < PCH; ++ch)
    v += pool_part[(size_t)(g*PCH + ch)*FD + f];
  v /= c;
  if (isf32) ((float*)out)[t] = v;
  else       ((ushort16*)out)[t] = f2bf(v);
}

// ---------------- launch ----------------

extern "C" void kernel_launch(void* const* d_in, const int* in_sizes, int n_in,
                              void* d_out, int out_size, void* d_ws, size_t ws_size,
                              hipStream_t stream)
{
  const void* x   = d_in[0];
  const void* ei  = d_in[1];
  const void* bat = d_in[2];
  const void* wl1 = d_in[3];
  const void* bl1 = d_in[4];
  const void* wr1 = d_in[5];
  const void* g1  = d_in[6];
  const void* be1 = d_in[7];
  const void* wl2 = d_in[8];
  const void* bl2 = d_in[9];
  const void* wr2 = d_in[10];
  const void* g2  = d_in[11];
  const void* be2 = d_in[12];
  char* ws = (char*)d_ws;

  // persistent
  uint32* gstart  = (uint32*)(ws + 64);           // 65 u32
  uint32* bbase   = (uint32*)(ws + 384);          // 197 u32
  float*  scale1  = (float*) (ws + 1280);
  float*  shift1  = (float*) (ws + 1792);
  float*  scale2  = (float*) (ws + 2304);
  float*  shift2  = (float*) (ws + 2816);
  uint32* rowstart= (uint32*)(ws + 3328);         // -> 203,328
  uint32* deg     = (uint32*)(ws + 203328);       // -> 403,328
  ushort16* colidx= (ushort16*)(ws + 403328);     // u16 -> 2,003,328
  uint32* part    = (uint32*)(ws + 2003328);      // 16*256 u32 -> 2,019,712
  uint32* pbase   = (uint32*)(ws + 2019712);      // 16*256 u32 -> 2,036,096
  short*  wfrag   = (short*) (ws + 2204032);      // 2 x 32768 shorts -> 2,335,104
  float*  bnpart  = (float*) (ws + 2335104);      // 782*256 f32 -> 3,135,872
  ushort16* xb    = (ushort16*)(ws + 3135872);    // 12.8 MB -> 15,935,872
  ushort16* aggb  = (ushort16*)(ws + 15935872);   // 12.8 MB -> 28,735,872
  ushort16* hp1   = (ushort16*)(ws + 28735872);   // 12.8 MB -> 41,535,872
  ushort16* hp2   = (ushort16*)(ws + 41535872);   // 12.8 MB -> 54,335,872
  // transient, inside hp1 (dead before gemm1 writes hp1):
  uint32* pack0   = (uint32*)(ws + 28735872);     // 3.2 MB
  uint32* pack1   = (uint32*)(ws + 31935872);     // 3.2 MB
  uint32* hist    = (uint32*)(ws + 35135872);     // 391*256 u32
  uint32* off     = (uint32*)(ws + 35536256);     // 391*256 u32
  // ppart overlaps pack0 region (pool runs after hp1's last read)
  float*  ppart   = (float*) (ws + 28735872);     // 2048*128 f32

  // CSR build + gseg + xcvt + wprep (one grid, no global atomics)
  pack_gseg_prep_kernel<<<GB + 196 + 3125 + 256, 256, 0, stream>>>(
      ei, bat, x, wl1, wr1, wl2, wr2, pack0, hist, gstart, xb, wfrag);
  scan_part_kernel <<<SBK, 256, 0, stream>>>(hist, part);
  scan_mid_kernel  <<<1,   256, 0, stream>>>(part, pbase, bbase);
  scan_off_kernel  <<<SBK, 256, 0, stream>>>(hist, pbase, off);
  scatter_kernel   <<<GB,  256, 0, stream>>>(pack0, off, pack1);
  bucket_csr_kernel<<<NBK, 256, 0, stream>>>(pack1, bbase, rowstart, deg, colidx);

  // layer 1 (reads x directly when bf16)
  agg_kernel<0>    <<<3125, 256, 0, stream>>>(xb, x, ei, rowstart, deg, colidx,
                                              nullptr, nullptr, aggb);
  gemm_bn_kernel<0><<<GB2,  256, 0, stream>>>(aggb, xb, x, ei, wfrag, bl1,
                                              nullptr, nullptr, x, hp1, bnpart);
  bn_final_kernel  <<<16,   256, 0, stream>>>(bnpart, g1, be1, x, ei, scale1, shift1);

  // layer 2 (BN1+ReLU fused into agg gather and gemm A1 operand)
  agg_kernel<1>    <<<3125, 256, 0, stream>>>(hp1, x, ei, rowstart, deg, colidx,
                                              scale1, shift1, aggb);
  gemm_bn_kernel<1><<<GB2,  256, 0, stream>>>(aggb, hp1, nullptr, ei, wfrag + 32768, bl2,
                                              scale1, shift1, x, hp2, bnpart);
  bn_final_kernel  <<<16,   256, 0, stream>>>(bnpart, g2, be2, x, ei, scale2, shift2);

  // pool (BN2 + ReLU fused)
  pool_partial_kernel<<<NGRAPH*PCH, 256, 0, stream>>>(hp2, scale2, shift2, gstart, ppart);
  pool_final_kernel  <<<32,  256, 0, stream>>>(ppart, gstart, x, ei, d_out);
}

// Round 15
// 248.892 us; speedup vs baseline: 1.2366x; 1.2366x over previous
//
#include <hip/hip_runtime.h>
#include <hip/hip_bf16.h>
#include <stdint.h>

typedef unsigned int uint32;
typedef unsigned short ushort16;

typedef __attribute__((ext_vector_type(8))) short short8;
typedef __attribute__((ext_vector_type(4))) float f32x4;
typedef __attribute__((ext_vector_type(2))) float f32x2;

#define N_NODES 50000
#define N_EDGES 800000
#define FD      128
#define NGRAPH  64
#define MTILES  3125   // N_NODES / 16 exactly
#define NBK     196    // coarse buckets = ceil(50000/256)
#define GB      391    // sort blocks (2048 edges each)
#define GB2     782    // gemm blocks (4 m-tiles each, 1 per wave)
#define PCH     32     // pool chunks per graph
#define SBK     16     // scan split blocks
#define KCH2    25     // ceil(391/16)

__device__ __forceinline__ float bf2f(ushort16 u){
  union { uint32 i; float f; } v; v.i = ((uint32)u) << 16; return v.f;
}
__device__ __forceinline__ float bf2f_lo(uint32 w){ union{uint32 i;float f;}v; v.i = w << 16; return v.f; }
__device__ __forceinline__ float bf2f_hi(uint32 w){ union{uint32 i;float f;}v; v.i = w & 0xffff0000u; return v.f; }
__device__ __forceinline__ ushort16 f2bf(float f){
  uint32 u = __float_as_uint(f);
  u += 0x7fffu + ((u >> 16) & 1u);   // round-to-nearest-even
  return (ushort16)(u >> 16);
}

__device__ __forceinline__ int ld_idx(const void* p, uint32 is64, size_t i){
  return is64 ? (int)((const long long*)p)[i] : ((const int*)p)[i];
}
__device__ __forceinline__ float ld_f(const void* p, uint32 isf32, int i){
  return isf32 ? ((const float*)p)[i] : bf2f(((const ushort16*)p)[i]);
}

// ---- fp8 e4m3 pack/unpack (HW converters on gfx950; bit-twiddle fallback) --
// NOTE: hi/word_sel operands of the cvt builtins must be compile-time
// constants (R14 compile failure) -> template on HI.
#if __has_builtin(__builtin_amdgcn_cvt_pk_f32_fp8) && __has_builtin(__builtin_amdgcn_cvt_pk_fp8_f32)
#define HW_FP8 1
#else
#define HW_FP8 0
#endif

template<bool HI>
__device__ __forceinline__ uint32 enc_pair(float f0, float f1, uint32 old){
#if HW_FP8
  return (uint32)__builtin_amdgcn_cvt_pk_fp8_f32(f0, f1, (int)old, HI);
#else
  uint32 r = old;
  float ff[2] = {f0, f1};
#pragma unroll
  for (int j = 0; j < 2; ++j){
    uint32 u = __float_as_uint(ff[j]);
    uint32 s = (u >> 31) << 7;
    uint32 au = u & 0x7FFFFFFFu;
    uint32 rr = au + 0x7FFFFu + ((au >> 20) & 1u);
    uint32 e = rr >> 23;
    uint32 q;
    if (e < 121u) q = s;                            // flush small to 0
    else { uint32 m8 = ((e - 120u) << 3) | ((rr >> 20) & 7u);
           if (m8 > 0x7Eu) m8 = 0x7Eu; q = s | m8; }
    int sh = (HI ? 16 : 0) + j*8;
    r = (r & ~(0xFFu << sh)) | (q << sh);
  }
  return r;
#endif
}

__device__ __forceinline__ uint32 enc4(float f0, float f1, float f2, float f3){
  uint32 w = enc_pair<false>(f0, f1, 0u);
  return enc_pair<true>(f2, f3, w);
}

__device__ __forceinline__ float dec1(uint32 b){
  uint32 em = b & 0x7Fu;
  float mag = (em >= 8u) ? __uint_as_float((em + 960u) << 20)
                         : (float)em * 0.001953125f;      // subnormals
  return (b & 0x80u) ? -mag : mag;
}

__device__ __forceinline__ void acc8f8(float* a, uint2 v){
#if HW_FP8
  f32x2 p0 = __builtin_amdgcn_cvt_pk_f32_fp8((int)v.x, false);
  f32x2 p1 = __builtin_amdgcn_cvt_pk_f32_fp8((int)v.x, true);
  f32x2 p2 = __builtin_amdgcn_cvt_pk_f32_fp8((int)v.y, false);
  f32x2 p3 = __builtin_amdgcn_cvt_pk_f32_fp8((int)v.y, true);
  a[0] += p0[0]; a[1] += p0[1]; a[2] += p1[0]; a[3] += p1[1];
  a[4] += p2[0]; a[5] += p2[1]; a[6] += p3[0]; a[7] += p3[1];
#else
#pragma unroll
  for (int j = 0; j < 4; ++j) a[j]     += dec1((v.x >> (j*8)) & 0xFFu);
#pragma unroll
  for (int j = 0; j < 4; ++j) a[4 + j] += dec1((v.y >> (j*8)) & 0xFFu);
#endif
}

// ---- inline dtype detection (per-wave, 2 broadcast loads + 2 ballots) ------
__device__ __forceinline__ void get_flags(const uint32* __restrict__ xw,
    const uint32* __restrict__ eiw, uint32& isf32, uint32& is64)
{
  int l = threadIdx.x & 63;
  uint32 w = xw[l];
  uint32 e8 = (w >> 7) & 0xFFu;              // exponent of the LOW bf16 half
  bool bf_like = (e8 >= 0x70u && e8 <= 0x82u);
  unsigned long long m = __ballot(bf_like);
  isf32 = (__popcll(m) < 32) ? 1u : 0u;
  uint32 hi = (l < 8) ? eiw[2*l + 1] : 1u;   // int64 high words are 0
  unsigned long long z = __ballot(hi == 0u);
  is64 = ((z & 0xFFull) == 0xFFull) ? 1u : 0u;
}

// ---------------- CSR build + gseg + prep, one grid -------------------------
// prep also emits x8 (fp8 copy of x) for the gather path.

__global__ __launch_bounds__(256) void pack_gseg_prep_kernel(
    const void* __restrict__ ei, const void* __restrict__ batch,
    const void* __restrict__ X,
    const void* __restrict__ WL1, const void* __restrict__ WR1,
    const void* __restrict__ WL2, const void* __restrict__ WR2,
    uint32* __restrict__ pack0, uint32* __restrict__ hist, uint32* __restrict__ gstart,
    ushort16* __restrict__ xb, uint2* __restrict__ x8, short* __restrict__ wfrag)
{
  uint32 isf32, is64;
  get_flags((const uint32*)X, (const uint32*)ei, isf32, is64);
  int tid = threadIdx.x;
  if (blockIdx.x < GB){
    __shared__ uint32 h[256];
    h[tid] = 0u;
    __syncthreads();
    int base = blockIdx.x*2048;
    for (int r = 0; r < 8; ++r){
      int i = base + r*256 + tid;
      if (i < N_EDGES){
        uint32 s = (uint32)ld_idx(ei, is64, i);
        uint32 d = (uint32)ld_idx(ei, is64, (size_t)N_EDGES + i);
        pack0[i] = (d << 16) | s;
        atomicAdd(&h[d >> 8], 1u);             // LDS atomic
      }
    }
    __syncthreads();
    hist[blockIdx.x*256 + tid] = h[tid];
  } else if (blockIdx.x < GB + 196){
    int t = (blockIdx.x - GB)*256 + tid;
    if (t >= N_NODES) return;
    int b1 = ld_idx(batch, is64, t);
    int b0 = (t == 0) ? -1 : ld_idx(batch, is64, t - 1);
    for (int g = b0 + 1; g <= b1; ++g) gstart[g] = (uint32)t;
    if (t == N_NODES - 1)
      for (int g = b1 + 1; g <= NGRAPH; ++g) gstart[g] = (uint32)N_NODES;
  } else if (blockIdx.x < GB + 196 + 3125){
    size_t e = ((size_t)(blockIdx.x - GB - 196)*256 + tid)*8;
    float f[8];
    if (isf32){
      const float* p = (const float*)X + e;
      float4 u = *(const float4*)p;
      float4 v = *(const float4*)(p + 4);
      f[0]=u.x; f[1]=u.y; f[2]=u.z; f[3]=u.w;
      f[4]=v.x; f[5]=v.y; f[6]=v.z; f[7]=v.w;
      uint4 o;
      o.x = (uint32)f2bf(f[0]) | ((uint32)f2bf(f[1]) << 16);
      o.y = (uint32)f2bf(f[2]) | ((uint32)f2bf(f[3]) << 16);
      o.z = (uint32)f2bf(f[4]) | ((uint32)f2bf(f[5]) << 16);
      o.w = (uint32)f2bf(f[6]) | ((uint32)f2bf(f[7]) << 16);
      *(uint4*)(xb + e) = o;
    } else {
      uint4 v = *(const uint4*)((const ushort16*)X + e);
      f[0]=bf2f_lo(v.x); f[1]=bf2f_hi(v.x); f[2]=bf2f_lo(v.y); f[3]=bf2f_hi(v.y);
      f[4]=bf2f_lo(v.z); f[5]=bf2f_hi(v.z); f[6]=bf2f_lo(v.w); f[7]=bf2f_hi(v.w);
    }
    uint32 w0 = enc4(f[0], f[1], f[2], f[3]);
    uint32 w1 = enc4(f[4], f[5], f[6], f[7]);
    x8[e >> 3] = (uint2){w0, w1};
  } else {
    int t = (blockIdx.x - GB - 196 - 3125)*256 + tid;   // 65536 total
    int layer = t >> 15;
    int r = t & 32767;
    int k = r >> 7, n = r & 127;
    const void* w = layer ? (k < 128 ? WL2 : WR2) : (k < 128 ? WL1 : WR1);
    int kk = k & 127;
    float wv = ld_f(w, isf32, kk*128 + n);
    int off = (((k >> 5)*8 + (n >> 4))*64 + (n & 15) + 16*((kk >> 3) & 3))*8 + (kk & 7);
    wfrag[layer*32768 + off] = (short)f2bf(wv);
  }
}

// ---------------- scan of hist, 3-phase (16 CUs instead of 1) ---------------

__global__ __launch_bounds__(256) void scan_part_kernel(const uint32* __restrict__ hist,
    uint32* __restrict__ part)
{
  int b = threadIdx.x, p = blockIdx.x;
  int k0 = p*KCH2, k1 = (k0 + KCH2 < GB) ? k0 + KCH2 : GB;
  uint32 sum = 0;
  for (int k = k0; k < k1; ++k) sum += hist[k*256 + b];
  part[p*256 + b] = sum;
}

__global__ __launch_bounds__(256) void scan_mid_kernel(const uint32* __restrict__ part,
    uint32* __restrict__ pbase, uint32* __restrict__ bbase)
{
  __shared__ uint32 lds[256];
  int b = threadIdx.x;
  uint32 tot = 0;
#pragma unroll
  for (int p = 0; p < SBK; ++p) tot += part[p*256 + b];
  uint32 x = tot;
  lds[b] = x; __syncthreads();
  for (int o = 1; o < 256; o <<= 1){
    uint32 y = (b >= o) ? lds[b - o] : 0u;
    __syncthreads();
    x += y; lds[b] = x;
    __syncthreads();
  }
  uint32 base = x - tot;                      // exclusive bucket base
  if (b <= NBK) bbase[b] = (b < NBK) ? base : (uint32)N_EDGES;
  uint32 run = base;
#pragma unroll
  for (int p = 0; p < SBK; ++p){
    pbase[p*256 + b] = run;
    run += part[p*256 + b];
  }
}

__global__ __launch_bounds__(256) void scan_off_kernel(const uint32* __restrict__ hist,
    const uint32* __restrict__ pbase, uint32* __restrict__ off)
{
  int b = threadIdx.x, p = blockIdx.x;
  int k0 = p*KCH2, k1 = (k0 + KCH2 < GB) ? k0 + KCH2 : GB;
  uint32 run = pbase[p*256 + b];
  for (int k = k0; k < k1; ++k){
    off[k*256 + b] = run;
    run += hist[k*256 + b];
  }
}

__global__ __launch_bounds__(256) void scatter_kernel(const uint32* __restrict__ pack0,
    const uint32* __restrict__ off, uint32* __restrict__ pack1)
{
  __shared__ uint32 cur[256];
  int tid = threadIdx.x;
  cur[tid] = off[blockIdx.x*256 + tid];
  __syncthreads();
  int base = blockIdx.x*2048;
  for (int r = 0; r < 8; ++r){
    int i = base + r*256 + tid;
    if (i < N_EDGES){
      uint32 p = pack0[i];
      uint32 pos = atomicAdd(&cur[p >> 24], 1u);   // LDS atomic
      pack1[pos] = p;
    }
  }
}

__global__ __launch_bounds__(256) void bucket_csr_kernel(const uint32* __restrict__ pack1,
    const uint32* __restrict__ bbase, uint32* __restrict__ rowstart,
    uint32* __restrict__ deg, ushort16* __restrict__ colidx)
{
  __shared__ uint32 cnt[256];
  __shared__ uint32 lds[256];
  __shared__ uint32 cur[256];
  int tid = threadIdx.x;
  int bk = blockIdx.x;
  uint32 e0 = bbase[bk], e1 = bbase[bk + 1];
  cnt[tid] = 0u;
  __syncthreads();
  for (uint32 i = e0 + tid; i < e1; i += 256)
    atomicAdd(&cnt[(pack1[i] >> 16) & 255u], 1u);  // LDS atomic
  __syncthreads();
  uint32 v = cnt[tid];
  uint32 x = v;
  lds[tid] = x; __syncthreads();
  for (int o = 1; o < 256; o <<= 1){
    uint32 y = (tid >= o) ? lds[tid - o] : 0u;
    __syncthreads();
    x += y; lds[tid] = x;
    __syncthreads();
  }
  uint32 start = e0 + x - v;
  int node = bk*256 + tid;
  if (node < N_NODES){ rowstart[node] = start; deg[node] = v; }
  cur[tid] = start;
  __syncthreads();
  for (uint32 i = e0 + tid; i < e1; i += 256){
    uint32 p = pack1[i];
    uint32 pos = atomicAdd(&cur[(p >> 16) & 255u], 1u);  // LDS atomic
    colidx[pos] = (ushort16)(p & 0xFFFFu);
  }
}

// ---------------- z8: fp8(relu(bn1(hp1))) for layer-2 gather ----------------

__global__ __launch_bounds__(256) void z8_kernel(const ushort16* __restrict__ hp,
    const float* __restrict__ scale, const float* __restrict__ shift,
    uint2* __restrict__ z8)
{
  size_t e = ((size_t)blockIdx.x*256 + threadIdx.x)*8;
  int c = (int)(e & 127);
  uint4 v = *(const uint4*)(hp + e);
  float f[8];
  f[0] = bf2f_lo(v.x); f[1] = bf2f_hi(v.x);
  f[2] = bf2f_lo(v.y); f[3] = bf2f_hi(v.y);
  f[4] = bf2f_lo(v.z); f[5] = bf2f_hi(v.z);
  f[6] = bf2f_lo(v.w); f[7] = bf2f_hi(v.w);
#pragma unroll
  for (int j = 0; j < 8; ++j)
    f[j] = fmaxf(f[j]*scale[c + j] + shift[c + j], 0.f);
  uint32 w0 = enc4(f[0], f[1], f[2], f[3]);
  uint32 w1 = enc4(f[4], f[5], f[6], f[7]);
  z8[e >> 3] = (uint2){w0, w1};
}

// ---------------- mean aggregation (pull, CSR, fp8 gather) ------------------
// 16 lanes per node; 8B (8 fp8 feats) per lane per edge -> 128B/row, half the
// LLC-miss bytes of the bf16 path. HW pk-converters decode. Output bf16.

__global__ __launch_bounds__(256) void agg_kernel(const uint2* __restrict__ X8,
    const uint32* __restrict__ rowstart, const uint32* __restrict__ deg,
    const ushort16* __restrict__ colidx, ushort16* __restrict__ out)
{
  int t = blockIdx.x*256 + threadIdx.x;
  int node = t >> 4;
  int l = t & 15;
  uint32 st = rowstart[node];
  uint32 d  = deg[node];
  float a[8];
#pragma unroll
  for (int j = 0; j < 8; ++j) a[j] = 0.f;
  const uint2* Xl = X8 + l;                     // row = 16 uint2; lane slot l
  uint32 i = 0;
  for (; i < d && ((st + i) & 3u); ++i){
    uint32 c = colidx[st + i];
    acc8f8(a, Xl[(size_t)c*16]);
  }
  for (; i + 8 <= d; i += 8){
    uint2 cA = *(const uint2*)(colidx + st + i);
    uint2 cB = *(const uint2*)(colidx + st + i + 4);
    uint2 v0 = Xl[(size_t)(cA.x & 0xFFFFu)*16];
    uint2 v1 = Xl[(size_t)(cA.x >> 16)*16];
    uint2 v2 = Xl[(size_t)(cA.y & 0xFFFFu)*16];
    uint2 v3 = Xl[(size_t)(cA.y >> 16)*16];
    uint2 v4 = Xl[(size_t)(cB.x & 0xFFFFu)*16];
    uint2 v5 = Xl[(size_t)(cB.x >> 16)*16];
    uint2 v6 = Xl[(size_t)(cB.y & 0xFFFFu)*16];
    uint2 v7 = Xl[(size_t)(cB.y >> 16)*16];
    acc8f8(a, v0); acc8f8(a, v1); acc8f8(a, v2); acc8f8(a, v3);
    acc8f8(a, v4); acc8f8(a, v5); acc8f8(a, v6); acc8f8(a, v7);
  }
  for (; i + 4 <= d; i += 4){
    uint2 cA = *(const uint2*)(colidx + st + i);
    uint2 v0 = Xl[(size_t)(cA.x & 0xFFFFu)*16];
    uint2 v1 = Xl[(size_t)(cA.x >> 16)*16];
    uint2 v2 = Xl[(size_t)(cA.y & 0xFFFFu)*16];
    uint2 v3 = Xl[(size_t)(cA.y >> 16)*16];
    acc8f8(a, v0); acc8f8(a, v1); acc8f8(a, v2); acc8f8(a, v3);
  }
  for (; i < d; ++i){
    uint32 c = colidx[st + i];
    acc8f8(a, Xl[(size_t)c*16]);
  }
  float inv = 1.f / fmaxf((float)d, 1.f);
  uint4 o;
  o.x = (uint32)f2bf(a[0]*inv) | ((uint32)f2bf(a[1]*inv) << 16);
  o.y = (uint32)f2bf(a[2]*inv) | ((uint32)f2bf(a[3]*inv) << 16);
  o.z = (uint32)f2bf(a[4]*inv) | ((uint32)f2bf(a[5]*inv) << 16);
  o.w = (uint32)f2bf(a[6]*inv) | ((uint32)f2bf(a[7]*inv) << 16);
  *(uint4*)(out + (size_t)node*FD + l*8) = o;
}

// ---------------- GEMM + bias + BN-stat partials (1 m-tile per wave) --------

__device__ __forceinline__ short8 affine_relu8(short8 a, const float* sc, const float* sh, int koff){
  short8 r;
#pragma unroll
  for (int j = 0; j < 8; ++j){
    float v = bf2f((ushort16)a[j]) * sc[koff + j] + sh[koff + j];
    r[j] = (short)f2bf(fmaxf(v, 0.f));
  }
  return r;
}

template<int APPLY>
__global__ __launch_bounds__(256) void gemm_bn_kernel(
    const ushort16* __restrict__ A0, const ushort16* __restrict__ A1d,
    const void* __restrict__ A1raw, const void* __restrict__ eiraw,
    const short* __restrict__ wfrag, const void* __restrict__ bias,
    const float* __restrict__ sc, const float* __restrict__ sh,
    const void* __restrict__ Xraw,
    ushort16* __restrict__ hpre, float* __restrict__ bnpart)
{
  __shared__ float red[256];
  uint32 isf32, is64;
  get_flags((const uint32*)Xraw, (const uint32*)eiraw, isf32, is64);
  const ushort16* A1 = (A1raw && !isf32) ? (const ushort16*)A1raw : A1d;
  int tid = threadIdx.x;
  red[tid] = 0.f;
  int wave = tid >> 6, lane = tid & 63, lq = lane >> 4, lm = lane & 15;
  int mt = blockIdx.x*4 + wave;
  bool valid = mt < MTILES;
  size_t m0 = (size_t)((valid ? mt : 0)*16 + lm);
  f32x4 acc[8];
#pragma unroll
  for (int i = 0; i < 8; ++i) acc[i] = (f32x4){0.f,0.f,0.f,0.f};

#pragma unroll
  for (int ks = 0; ks < 8; ++ks){
    int koff = (ks & 3)*32 + lq*8;
    const short* srcp = (const short*)(ks < 4 ? A0 : A1);
    short8 a = *(const short8*)(srcp + m0*FD + koff);
    if (APPLY && ks >= 4) a = affine_relu8(a, sc, sh, koff);
#pragma unroll
    for (int nt = 0; nt < 8; ++nt){
      short8 b = *(const short8*)&wfrag[((ks*8 + nt)*64 + lane)*8];
      acc[nt] = __builtin_amdgcn_mfma_f32_16x16x32_bf16(a, b, acc[nt], 0, 0, 0);
    }
  }

  __syncthreads();                              // red[] zero-init visible
#pragma unroll
  for (int nt = 0; nt < 8; ++nt){
    int colc = nt*16 + lm;                      // C/D: col = lane&15
    float bb = ld_f(bias, isf32, colc);
    float s = 0.f, s2 = 0.f;
    if (valid){
      size_t nb = (size_t)mt*16 + lq*4;         // C/D: row = quad*4 + reg
#pragma unroll
      for (int r = 0; r < 4; ++r){
        float val = acc[nt][r] + bb;
        hpre[(nb + r)*FD + colc] = f2bf(val);
        s += val; s2 += val*val;
      }
    }
    s  += __shfl_xor(s, 16);  s  += __shfl_xor(s, 32);
    s2 += __shfl_xor(s2, 16); s2 += __shfl_xor(s2, 32);
    if (lq == 0){
      atomicAdd(&red[colc], s);                 // LDS atomic
      atomicAdd(&red[128 + colc], s2);
    }
  }
  __syncthreads();
  bnpart[blockIdx.x*256 + tid] = red[tid];
}

// ---------------- BN finalize (16 blocks, shfl reduce) ----------------------

__global__ __launch_bounds__(256) void bn_final_kernel(const float* __restrict__ bnpart,
    const void* __restrict__ gamma, const void* __restrict__ beta,
    const void* __restrict__ Xraw, const void* __restrict__ eiraw,
    float* __restrict__ scale, float* __restrict__ shift)
{
  uint32 isf32, is64;
  get_flags((const uint32*)Xraw, (const uint32*)eiraw, isf32, is64);
  int tid = threadIdx.x;
  int f = blockIdx.x*8 + (tid >> 5);
  int l = tid & 31;
  float s = 0.f, q = 0.f;
  for (int b = l; b < GB2; b += 32){
    s += bnpart[b*256 + f];
    q += bnpart[b*256 + 128 + f];
  }
#pragma unroll
  for (int m = 16; m >= 1; m >>= 1){
    s += __shfl_xor(s, m);
    q += __shfl_xor(q, m);
  }
  if (l == 0){
    const float invN = 1.0f / (float)N_NODES;
    float mu  = s * invN;
    float var = q * invN - mu*mu;
    float scv = ld_f(gamma, isf32, f) * rsqrtf(var + 1e-5f);
    scale[f] = scv;
    shift[f] = ld_f(beta, isf32, f) - mu * scv;
  }
}

// ---------------- pool (BN2 + ReLU fused), high-occupancy -------------------

__global__ __launch_bounds__(256) void pool_partial_kernel(const ushort16* __restrict__ hp,
    const float* __restrict__ scale, const float* __restrict__ shift,
    const uint32* __restrict__ gstart, float* __restrict__ pool_part)
{
  __shared__ float wred[4*16*8];                 // 2 KB
  int tid = threadIdx.x;
  int g = blockIdx.x >> 5, chunk = blockIdx.x & 31;
  int slot = tid >> 4, l = tid & 15;
  int wave = tid >> 6, lane = tid & 63;
  uint32 st = gstart[g], cnt = gstart[g+1] - st;
  uint32 per = (cnt + PCH - 1) >> 5;
  uint32 b0 = st + chunk*per;
  uint32 b1 = b0 + per;
  uint32 e1 = st + cnt;
  if (b1 > e1) b1 = e1;
  float s0[8], h0[8], a[8];
#pragma unroll
  for (int j = 0; j < 8; ++j){ s0[j] = scale[l*8 + j]; h0[j] = shift[l*8 + j]; a[j] = 0.f; }
  for (uint32 n = b0 + slot; n < b1; n += 16){
    const uint4 v = *(const uint4*)(hp + (size_t)n*FD + l*8);
    float f[8];
    f[0] = bf2f_lo(v.x); f[1] = bf2f_hi(v.x);
    f[2] = bf2f_lo(v.y); f[3] = bf2f_hi(v.y);
    f[4] = bf2f_lo(v.z); f[5] = bf2f_hi(v.z);
    f[6] = bf2f_lo(v.w); f[7] = bf2f_hi(v.w);
#pragma unroll
    for (int j = 0; j < 8; ++j) a[j] += fmaxf(f[j]*s0[j] + h0[j], 0.f);
  }
#pragma unroll
  for (int j = 0; j < 8; ++j){
    a[j] += __shfl_xor(a[j], 16);
    a[j] += __shfl_xor(a[j], 32);
  }
  if (lane < 16){
#pragma unroll
    for (int j = 0; j < 8; ++j) wred[(wave*16 + lane)*8 + j] = a[j];
  }
  __syncthreads();
  if (tid < 16){
    float r[8];
#pragma unroll
    for (int j = 0; j < 8; ++j)
      r[j] = wred[(0*16 + tid)*8 + j] + wred[(1*16 + tid)*8 + j]
           + wred[(2*16 + tid)*8 + j] + wred[(3*16 + tid)*8 + j];
    float* dst = pool_part + (size_t)blockIdx.x*FD + tid*8;
#pragma unroll
    for (int j = 0; j < 8; ++j) dst[j] = r[j];
  }
}

__global__ void pool_final_kernel(const float* __restrict__ pool_part,
    const uint32* __restrict__ gstart, const void* __restrict__ Xraw,
    const void* __restrict__ eiraw, void* __restrict__ out)
{
  uint32 isf32, is64;
  get_flags((const uint32*)Xraw, (const uint32*)eiraw, isf32, is64);
  int t = blockIdx.x*256 + threadIdx.x;          // t < 8192
  int g = t >> 7, f = t & 127;
  float c = fmaxf((float)(gstart[g+1] - gstart[g]), 1.f);
  float v = 0.f;
#pragma unroll 8
  for (int ch = 0; ch < PCH; ++ch)
    v += pool_part[(size_t)(g*PCH + ch)*FD + f];
  v /= c;
  if (isf32) ((float*)out)[t] = v;
  else       ((ushort16*)out)[t] = f2bf(v);
}

// ---------------- launch ----------------

extern "C" void kernel_launch(void* const* d_in, const int* in_sizes, int n_in,
                              void* d_out, int out_size, void* d_ws, size_t ws_size,
                              hipStream_t stream)
{
  const void* x   = d_in[0];
  const void* ei  = d_in[1];
  const void* bat = d_in[2];
  const void* wl1 = d_in[3];
  const void* bl1 = d_in[4];
  const void* wr1 = d_in[5];
  const void* g1  = d_in[6];
  const void* be1 = d_in[7];
  const void* wl2 = d_in[8];
  const void* bl2 = d_in[9];
  const void* wr2 = d_in[10];
  const void* g2  = d_in[11];
  const void* be2 = d_in[12];
  char* ws = (char*)d_ws;

  // persistent
  uint32* gstart  = (uint32*)(ws + 64);           // 65 u32
  uint32* bbase   = (uint32*)(ws + 384);          // 197 u32
  float*  scale1  = (float*) (ws + 1280);
  float*  shift1  = (float*) (ws + 1792);
  float*  scale2  = (float*) (ws + 2304);
  float*  shift2  = (float*) (ws + 2816);
  uint32* rowstart= (uint32*)(ws + 3328);         // -> 203,328
  uint32* deg     = (uint32*)(ws + 203328);       // -> 403,328
  ushort16* colidx= (ushort16*)(ws + 403328);     // u16 -> 2,003,328
  uint32* part    = (uint32*)(ws + 2003328);      // 16*256 u32 -> 2,019,712
  uint32* pbase   = (uint32*)(ws + 2019712);      // 16*256 u32 -> 2,036,096
  short*  wfrag   = (short*) (ws + 2204032);      // 2 x 32768 shorts -> 2,335,104
  float*  bnpart  = (float*) (ws + 2335104);      // 782*256 f32 -> 3,135,872
  ushort16* xb    = (ushort16*)(ws + 3135872);    // 12.8 MB -> 15,935,872
  ushort16* aggb  = (ushort16*)(ws + 15935872);   // 12.8 MB -> 28,735,872
  ushort16* hp1   = (ushort16*)(ws + 28735872);   // 12.8 MB -> 41,535,872
  ushort16* hp2   = (ushort16*)(ws + 41535872);   // 12.8 MB -> 54,335,872
  // x8 (6.4 MB) aliases hp2's first half: last read (agg1) precedes gemm2's write.
  uint2*  x8      = (uint2*) (ws + 41535872);
  // z8 (6.4 MB) aliases xb: xb's last read (gemm1 A1) precedes z8's write.
  uint2*  z8      = (uint2*) (ws + 3135872);
  // transient, inside hp1 (dead before gemm1 writes hp1):
  uint32* pack0   = (uint32*)(ws + 28735872);     // 3.2 MB
  uint32* pack1   = (uint32*)(ws + 31935872);     // 3.2 MB
  uint32* hist    = (uint32*)(ws + 35135872);     // 391*256 u32
  uint32* off     = (uint32*)(ws + 35536256);     // 391*256 u32
  // ppart overlaps pack0 region (pool runs after hp1's last read)
  float*  ppart   = (float*) (ws + 28735872);     // 2048*128 f32

  // CSR build + gseg + xcvt(+fp8) + wprep (one grid, no global atomics)
  pack_gseg_prep_kernel<<<GB + 196 + 3125 + 256, 256, 0, stream>>>(
      ei, bat, x, wl1, wr1, wl2, wr2, pack0, hist, gstart, xb, x8, wfrag);
  scan_part_kernel <<<SBK, 256, 0, stream>>>(hist, part);
  scan_mid_kernel  <<<1,   256, 0, stream>>>(part, pbase, bbase);
  scan_off_kernel  <<<SBK, 256, 0, stream>>>(hist, pbase, off);
  scatter_kernel   <<<GB,  256, 0, stream>>>(pack0, off, pack1);
  bucket_csr_kernel<<<NBK, 256, 0, stream>>>(pack1, bbase, rowstart, deg, colidx);

  // layer 1 (fp8 gather of x)
  agg_kernel       <<<3125, 256, 0, stream>>>(x8, rowstart, deg, colidx, aggb);
  gemm_bn_kernel<0><<<GB2,  256, 0, stream>>>(aggb, xb, x, ei, wfrag, bl1,
                                              nullptr, nullptr, x, hp1, bnpart);
  bn_final_kernel  <<<16,   256, 0, stream>>>(bnpart, g1, be1, x, ei, scale1, shift1);

  // layer 2 (z8 = fp8(relu(bn1(hp1))); gather z8; gemm A1 = affine(hp1) bf16)
  z8_kernel        <<<3125, 256, 0, stream>>>(hp1, scale1, shift1, z8);
  agg_kernel       <<<3125, 256, 0, stream>>>(z8, rowstart, deg, colidx, aggb);
  gemm_bn_kernel<1><<<GB2,  256, 0, stream>>>(aggb, hp1, nullptr, ei, wfrag + 32768, bl2,
                                              scale1, shift1, x, hp2, bnpart);
  bn_final_kernel  <<<16,   256, 0, stream>>>(bnpart, g2, be2, x, ei, scale2, shift2);

  // pool (BN2 + ReLU fused)
  pool_partial_kernel<<<NGRAPH*PCH, 256, 0, stream>>>(hp2, scale2, shift2, gstart, ppart);
  pool_final_kernel  <<<32,  256, 0, stream>>>(ppart, gstart, x, ei, d_out);
}

// Round 16
// 242.209 us; speedup vs baseline: 1.2707x; 1.0276x over previous
//
#include <hip/hip_runtime.h>
#include <hip/hip_bf16.h>
#include <stdint.h>

typedef unsigned int uint32;
typedef unsigned short ushort16;

typedef __attribute__((ext_vector_type(8))) short short8;
typedef __attribute__((ext_vector_type(4))) float f32x4;
typedef __attribute__((ext_vector_type(2))) float f32x2;

#define N_NODES 50000
#define N_EDGES 800000
#define FD      128
#define NGRAPH  64
#define MTILES  3125   // N_NODES / 16 exactly
#define NBK     196    // coarse buckets = ceil(50000/256)
#define GB      391    // sort blocks (2048 edges each)
#define GB2     782    // gemm blocks (4 m-tiles each, 1 per wave)
#define PCH     32     // pool chunks per graph
#define SBK     16     // scan split blocks
#define KCH2    25     // ceil(391/16)

__device__ __forceinline__ float bf2f(ushort16 u){
  union { uint32 i; float f; } v; v.i = ((uint32)u) << 16; return v.f;
}
__device__ __forceinline__ float bf2f_lo(uint32 w){ union{uint32 i;float f;}v; v.i = w << 16; return v.f; }
__device__ __forceinline__ float bf2f_hi(uint32 w){ union{uint32 i;float f;}v; v.i = w & 0xffff0000u; return v.f; }
__device__ __forceinline__ ushort16 f2bf(float f){
  uint32 u = __float_as_uint(f);
  u += 0x7fffu + ((u >> 16) & 1u);   // round-to-nearest-even
  return (ushort16)(u >> 16);
}

__device__ __forceinline__ int ld_idx(const void* p, uint32 is64, size_t i){
  return is64 ? (int)((const long long*)p)[i] : ((const int*)p)[i];
}
__device__ __forceinline__ float ld_f(const void* p, uint32 isf32, int i){
  return isf32 ? ((const float*)p)[i] : bf2f(((const ushort16*)p)[i]);
}

// ---- fp8 e4m3 pack/unpack (HW converters on gfx950; bit-twiddle fallback) --
// hi/word_sel operands of the cvt builtins must be compile-time constants.
#if __has_builtin(__builtin_amdgcn_cvt_pk_f32_fp8) && __has_builtin(__builtin_amdgcn_cvt_pk_fp8_f32)
#define HW_FP8 1
#else
#define HW_FP8 0
#endif

template<bool HI>
__device__ __forceinline__ uint32 enc_pair(float f0, float f1, uint32 old){
#if HW_FP8
  return (uint32)__builtin_amdgcn_cvt_pk_fp8_f32(f0, f1, (int)old, HI);
#else
  uint32 r = old;
  float ff[2] = {f0, f1};
#pragma unroll
  for (int j = 0; j < 2; ++j){
    uint32 u = __float_as_uint(ff[j]);
    uint32 s = (u >> 31) << 7;
    uint32 au = u & 0x7FFFFFFFu;
    uint32 rr = au + 0x7FFFFu + ((au >> 20) & 1u);
    uint32 e = rr >> 23;
    uint32 q;
    if (e < 121u) q = s;                            // flush small to 0
    else { uint32 m8 = ((e - 120u) << 3) | ((rr >> 20) & 7u);
           if (m8 > 0x7Eu) m8 = 0x7Eu; q = s | m8; }
    int sh = (HI ? 16 : 0) + j*8;
    r = (r & ~(0xFFu << sh)) | (q << sh);
  }
  return r;
#endif
}

__device__ __forceinline__ uint32 enc4(float f0, float f1, float f2, float f3){
  uint32 w = enc_pair<false>(f0, f1, 0u);
  return enc_pair<true>(f2, f3, w);
}

__device__ __forceinline__ float dec1(uint32 b){
  uint32 em = b & 0x7Fu;
  float mag = (em >= 8u) ? __uint_as_float((em + 960u) << 20)
                         : (float)em * 0.001953125f;      // subnormals
  return (b & 0x80u) ? -mag : mag;
}

__device__ __forceinline__ void acc8f8(float* a, uint2 v){
#if HW_FP8
  f32x2 p0 = __builtin_amdgcn_cvt_pk_f32_fp8((int)v.x, false);
  f32x2 p1 = __builtin_amdgcn_cvt_pk_f32_fp8((int)v.x, true);
  f32x2 p2 = __builtin_amdgcn_cvt_pk_f32_fp8((int)v.y, false);
  f32x2 p3 = __builtin_amdgcn_cvt_pk_f32_fp8((int)v.y, true);
  a[0] += p0[0]; a[1] += p0[1]; a[2] += p1[0]; a[3] += p1[1];
  a[4] += p2[0]; a[5] += p2[1]; a[6] += p3[0]; a[7] += p3[1];
#else
#pragma unroll
  for (int j = 0; j < 4; ++j) a[j]     += dec1((v.x >> (j*8)) & 0xFFu);
#pragma unroll
  for (int j = 0; j < 4; ++j) a[4 + j] += dec1((v.y >> (j*8)) & 0xFFu);
#endif
}

// fp8x8 -> bf16x8 (exact: e4m3 values are representable in bf16)
__device__ __forceinline__ short8 dec8bf(uint2 v){
  short8 r;
#if HW_FP8
  f32x2 p0 = __builtin_amdgcn_cvt_pk_f32_fp8((int)v.x, false);
  f32x2 p1 = __builtin_amdgcn_cvt_pk_f32_fp8((int)v.x, true);
  f32x2 p2 = __builtin_amdgcn_cvt_pk_f32_fp8((int)v.y, false);
  f32x2 p3 = __builtin_amdgcn_cvt_pk_f32_fp8((int)v.y, true);
  r[0] = (short)f2bf(p0[0]); r[1] = (short)f2bf(p0[1]);
  r[2] = (short)f2bf(p1[0]); r[3] = (short)f2bf(p1[1]);
  r[4] = (short)f2bf(p2[0]); r[5] = (short)f2bf(p2[1]);
  r[6] = (short)f2bf(p3[0]); r[7] = (short)f2bf(p3[1]);
#else
#pragma unroll
  for (int j = 0; j < 4; ++j) r[j]     = (short)f2bf(dec1((v.x >> (j*8)) & 0xFFu));
#pragma unroll
  for (int j = 0; j < 4; ++j) r[4 + j] = (short)f2bf(dec1((v.y >> (j*8)) & 0xFFu));
#endif
  return r;
}

// ---- inline dtype detection (per-wave, 2 broadcast loads + 2 ballots) ------
__device__ __forceinline__ void get_flags(const uint32* __restrict__ xw,
    const uint32* __restrict__ eiw, uint32& isf32, uint32& is64)
{
  int l = threadIdx.x & 63;
  uint32 w = xw[l];
  uint32 e8 = (w >> 7) & 0xFFu;              // exponent of the LOW bf16 half
  bool bf_like = (e8 >= 0x70u && e8 <= 0x82u);
  unsigned long long m = __ballot(bf_like);
  isf32 = (__popcll(m) < 32) ? 1u : 0u;
  uint32 hi = (l < 8) ? eiw[2*l + 1] : 1u;   // int64 high words are 0
  unsigned long long z = __ballot(hi == 0u);
  is64 = ((z & 0xFFull) == 0xFFull) ? 1u : 0u;
}

// ---------------- CSR build + gseg + prep, one grid -------------------------
// prep emits x8 (fp8 copy of x) — the only form of x the compute path reads.

__global__ __launch_bounds__(256) void pack_gseg_prep_kernel(
    const void* __restrict__ ei, const void* __restrict__ batch,
    const void* __restrict__ X,
    const void* __restrict__ WL1, const void* __restrict__ WR1,
    const void* __restrict__ WL2, const void* __restrict__ WR2,
    uint32* __restrict__ pack0, uint32* __restrict__ hist, uint32* __restrict__ gstart,
    uint2* __restrict__ x8, short* __restrict__ wfrag)
{
  uint32 isf32, is64;
  get_flags((const uint32*)X, (const uint32*)ei, isf32, is64);
  int tid = threadIdx.x;
  if (blockIdx.x < GB){
    __shared__ uint32 h[256];
    h[tid] = 0u;
    __syncthreads();
    int base = blockIdx.x*2048;
    for (int r = 0; r < 8; ++r){
      int i = base + r*256 + tid;
      if (i < N_EDGES){
        uint32 s = (uint32)ld_idx(ei, is64, i);
        uint32 d = (uint32)ld_idx(ei, is64, (size_t)N_EDGES + i);
        pack0[i] = (d << 16) | s;
        atomicAdd(&h[d >> 8], 1u);             // LDS atomic
      }
    }
    __syncthreads();
    hist[blockIdx.x*256 + tid] = h[tid];
  } else if (blockIdx.x < GB + 196){
    int t = (blockIdx.x - GB)*256 + tid;
    if (t >= N_NODES) return;
    int b1 = ld_idx(batch, is64, t);
    int b0 = (t == 0) ? -1 : ld_idx(batch, is64, t - 1);
    for (int g = b0 + 1; g <= b1; ++g) gstart[g] = (uint32)t;
    if (t == N_NODES - 1)
      for (int g = b1 + 1; g <= NGRAPH; ++g) gstart[g] = (uint32)N_NODES;
  } else if (blockIdx.x < GB + 196 + 3125){
    size_t e = ((size_t)(blockIdx.x - GB - 196)*256 + tid)*8;
    float f[8];
    if (isf32){
      const float* p = (const float*)X + e;
      float4 u = *(const float4*)p;
      float4 v = *(const float4*)(p + 4);
      f[0]=u.x; f[1]=u.y; f[2]=u.z; f[3]=u.w;
      f[4]=v.x; f[5]=v.y; f[6]=v.z; f[7]=v.w;
    } else {
      uint4 v = *(const uint4*)((const ushort16*)X + e);
      f[0]=bf2f_lo(v.x); f[1]=bf2f_hi(v.x); f[2]=bf2f_lo(v.y); f[3]=bf2f_hi(v.y);
      f[4]=bf2f_lo(v.z); f[5]=bf2f_hi(v.z); f[6]=bf2f_lo(v.w); f[7]=bf2f_hi(v.w);
    }
    uint32 w0 = enc4(f[0], f[1], f[2], f[3]);
    uint32 w1 = enc4(f[4], f[5], f[6], f[7]);
    x8[e >> 3] = (uint2){w0, w1};
  } else {
    int t = (blockIdx.x - GB - 196 - 3125)*256 + tid;   // 65536 total
    int layer = t >> 15;
    int r = t & 32767;
    int k = r >> 7, n = r & 127;
    const void* w = layer ? (k < 128 ? WL2 : WR2) : (k < 128 ? WL1 : WR1);
    int kk = k & 127;
    float wv = ld_f(w, isf32, kk*128 + n);
    int off = (((k >> 5)*8 + (n >> 4))*64 + (n & 15) + 16*((kk >> 3) & 3))*8 + (kk & 7);
    wfrag[layer*32768 + off] = (short)f2bf(wv);
  }
}

// ---------------- scan of hist, 3-phase (16 CUs instead of 1) ---------------

__global__ __launch_bounds__(256) void scan_part_kernel(const uint32* __restrict__ hist,
    uint32* __restrict__ part)
{
  int b = threadIdx.x, p = blockIdx.x;
  int k0 = p*KCH2, k1 = (k0 + KCH2 < GB) ? k0 + KCH2 : GB;
  uint32 sum = 0;
  for (int k = k0; k < k1; ++k) sum += hist[k*256 + b];
  part[p*256 + b] = sum;
}

__global__ __launch_bounds__(256) void scan_mid_kernel(const uint32* __restrict__ part,
    uint32* __restrict__ pbase, uint32* __restrict__ bbase)
{
  __shared__ uint32 lds[256];
  int b = threadIdx.x;
  uint32 tot = 0;
#pragma unroll
  for (int p = 0; p < SBK; ++p) tot += part[p*256 + b];
  uint32 x = tot;
  lds[b] = x; __syncthreads();
  for (int o = 1; o < 256; o <<= 1){
    uint32 y = (b >= o) ? lds[b - o] : 0u;
    __syncthreads();
    x += y; lds[b] = x;
    __syncthreads();
  }
  uint32 base = x - tot;                      // exclusive bucket base
  if (b <= NBK) bbase[b] = (b < NBK) ? base : (uint32)N_EDGES;
  uint32 run = base;
#pragma unroll
  for (int p = 0; p < SBK; ++p){
    pbase[p*256 + b] = run;
    run += part[p*256 + b];
  }
}

__global__ __launch_bounds__(256) void scan_off_kernel(const uint32* __restrict__ hist,
    const uint32* __restrict__ pbase, uint32* __restrict__ off)
{
  int b = threadIdx.x, p = blockIdx.x;
  int k0 = p*KCH2, k1 = (k0 + KCH2 < GB) ? k0 + KCH2 : GB;
  uint32 run = pbase[p*256 + b];
  for (int k = k0; k < k1; ++k){
    off[k*256 + b] = run;
    run += hist[k*256 + b];
  }
}

__global__ __launch_bounds__(256) void scatter_kernel(const uint32* __restrict__ pack0,
    const uint32* __restrict__ off, uint32* __restrict__ pack1)
{
  __shared__ uint32 cur[256];
  int tid = threadIdx.x;
  cur[tid] = off[blockIdx.x*256 + tid];
  __syncthreads();
  int base = blockIdx.x*2048;
  for (int r = 0; r < 8; ++r){
    int i = base + r*256 + tid;
    if (i < N_EDGES){
      uint32 p = pack0[i];
      uint32 pos = atomicAdd(&cur[p >> 24], 1u);   // LDS atomic
      pack1[pos] = p;
    }
  }
}

__global__ __launch_bounds__(256) void bucket_csr_kernel(const uint32* __restrict__ pack1,
    const uint32* __restrict__ bbase, uint32* __restrict__ rowstart,
    uint32* __restrict__ deg, ushort16* __restrict__ colidx)
{
  __shared__ uint32 cnt[256];
  __shared__ uint32 lds[256];
  __shared__ uint32 cur[256];
  int tid = threadIdx.x;
  int bk = blockIdx.x;
  uint32 e0 = bbase[bk], e1 = bbase[bk + 1];
  cnt[tid] = 0u;
  __syncthreads();
  for (uint32 i = e0 + tid; i < e1; i += 256)
    atomicAdd(&cnt[(pack1[i] >> 16) & 255u], 1u);  // LDS atomic
  __syncthreads();
  uint32 v = cnt[tid];
  uint32 x = v;
  lds[tid] = x; __syncthreads();
  for (int o = 1; o < 256; o <<= 1){
    uint32 y = (tid >= o) ? lds[tid - o] : 0u;
    __syncthreads();
    x += y; lds[tid] = x;
    __syncthreads();
  }
  uint32 start = e0 + x - v;
  int node = bk*256 + tid;
  if (node < N_NODES){ rowstart[node] = start; deg[node] = v; }
  cur[tid] = start;
  __syncthreads();
  for (uint32 i = e0 + tid; i < e1; i += 256){
    uint32 p = pack1[i];
    uint32 pos = atomicAdd(&cur[(p >> 16) & 255u], 1u);  // LDS atomic
    colidx[pos] = (ushort16)(p & 0xFFFFu);
  }
}

// ---------------- z8: fp8(relu(bn1(hp1))) for layer-2 gather + self ---------

__global__ __launch_bounds__(256) void z8_kernel(const ushort16* __restrict__ hp,
    const float* __restrict__ scale, const float* __restrict__ shift,
    uint2* __restrict__ z8)
{
  size_t e = ((size_t)blockIdx.x*256 + threadIdx.x)*8;
  int c = (int)(e & 127);
  uint4 v = *(const uint4*)(hp + e);
  float f[8];
  f[0] = bf2f_lo(v.x); f[1] = bf2f_hi(v.x);
  f[2] = bf2f_lo(v.y); f[3] = bf2f_hi(v.y);
  f[4] = bf2f_lo(v.z); f[5] = bf2f_hi(v.z);
  f[6] = bf2f_lo(v.w); f[7] = bf2f_hi(v.w);
#pragma unroll
  for (int j = 0; j < 8; ++j)
    f[j] = fmaxf(f[j]*scale[c + j] + shift[c + j], 0.f);
  uint32 w0 = enc4(f[0], f[1], f[2], f[3]);
  uint32 w1 = enc4(f[4], f[5], f[6], f[7]);
  z8[e >> 3] = (uint2){w0, w1};
}

// ---------------- mean aggregation (pull, CSR, fp8 gather, fp8 out) ---------
// 16 lanes per node; 8B (8 fp8 feats) per lane per edge. Output fp8 (agg8).

__global__ __launch_bounds__(256) void agg_kernel(const uint2* __restrict__ X8,
    const uint32* __restrict__ rowstart, const uint32* __restrict__ deg,
    const ushort16* __restrict__ colidx, uint2* __restrict__ out8)
{
  int t = blockIdx.x*256 + threadIdx.x;
  int node = t >> 4;
  int l = t & 15;
  uint32 st = rowstart[node];
  uint32 d  = deg[node];
  float a[8];
#pragma unroll
  for (int j = 0; j < 8; ++j) a[j] = 0.f;
  const uint2* Xl = X8 + l;                     // row = 16 uint2; lane slot l
  uint32 i = 0;
  for (; i < d && ((st + i) & 3u); ++i){
    uint32 c = colidx[st + i];
    acc8f8(a, Xl[(size_t)c*16]);
  }
  for (; i + 8 <= d; i += 8){
    uint2 cA = *(const uint2*)(colidx + st + i);
    uint2 cB = *(const uint2*)(colidx + st + i + 4);
    uint2 v0 = Xl[(size_t)(cA.x & 0xFFFFu)*16];
    uint2 v1 = Xl[(size_t)(cA.x >> 16)*16];
    uint2 v2 = Xl[(size_t)(cA.y & 0xFFFFu)*16];
    uint2 v3 = Xl[(size_t)(cA.y >> 16)*16];
    uint2 v4 = Xl[(size_t)(cB.x & 0xFFFFu)*16];
    uint2 v5 = Xl[(size_t)(cB.x >> 16)*16];
    uint2 v6 = Xl[(size_t)(cB.y & 0xFFFFu)*16];
    uint2 v7 = Xl[(size_t)(cB.y >> 16)*16];
    acc8f8(a, v0); acc8f8(a, v1); acc8f8(a, v2); acc8f8(a, v3);
    acc8f8(a, v4); acc8f8(a, v5); acc8f8(a, v6); acc8f8(a, v7);
  }
  for (; i + 4 <= d; i += 4){
    uint2 cA = *(const uint2*)(colidx + st + i);
    uint2 v0 = Xl[(size_t)(cA.x & 0xFFFFu)*16];
    uint2 v1 = Xl[(size_t)(cA.x >> 16)*16];
    uint2 v2 = Xl[(size_t)(cA.y & 0xFFFFu)*16];
    uint2 v3 = Xl[(size_t)(cA.y >> 16)*16];
    acc8f8(a, v0); acc8f8(a, v1); acc8f8(a, v2); acc8f8(a, v3);
  }
  for (; i < d; ++i){
    uint32 c = colidx[st + i];
    acc8f8(a, Xl[(size_t)c*16]);
  }
  float inv = 1.f / fmaxf((float)d, 1.f);
  uint2 o8;
  o8.x = enc4(a[0]*inv, a[1]*inv, a[2]*inv, a[3]*inv);
  o8.y = enc4(a[4]*inv, a[5]*inv, a[6]*inv, a[7]*inv);
  out8[(size_t)node*16 + l] = o8;
}

// ---------------- GEMM + bias + BN-stat partials (1 m-tile per wave) --------
// Both A operands are fp8 rows (agg8 + x8/z8); decoded to bf16 for MFMA.

__global__ __launch_bounds__(256) void gemm_bn_kernel(
    const uint2* __restrict__ A0, const uint2* __restrict__ A1,
    const void* __restrict__ eiraw,
    const short* __restrict__ wfrag, const void* __restrict__ bias,
    const void* __restrict__ Xraw,
    ushort16* __restrict__ hpre, float* __restrict__ bnpart)
{
  __shared__ float red[256];
  uint32 isf32, is64;
  get_flags((const uint32*)Xraw, (const uint32*)eiraw, isf32, is64);
  int tid = threadIdx.x;
  red[tid] = 0.f;
  int wave = tid >> 6, lane = tid & 63, lq = lane >> 4, lm = lane & 15;
  int mt = blockIdx.x*4 + wave;
  bool valid = mt < MTILES;
  size_t m0 = (size_t)((valid ? mt : 0)*16 + lm);
  f32x4 acc[8];
#pragma unroll
  for (int i = 0; i < 8; ++i) acc[i] = (f32x4){0.f,0.f,0.f,0.f};

#pragma unroll
  for (int ks = 0; ks < 8; ++ks){
    const uint2* srcp = (ks < 4) ? A0 : A1;
    uint2 av8 = srcp[m0*16 + (ks & 3)*4 + lq];
    short8 a = dec8bf(av8);
#pragma unroll
    for (int nt = 0; nt < 8; ++nt){
      short8 b = *(const short8*)&wfrag[((ks*8 + nt)*64 + lane)*8];
      acc[nt] = __builtin_amdgcn_mfma_f32_16x16x32_bf16(a, b, acc[nt], 0, 0, 0);
    }
  }

  __syncthreads();                              // red[] zero-init visible
#pragma unroll
  for (int nt = 0; nt < 8; ++nt){
    int colc = nt*16 + lm;                      // C/D: col = lane&15
    float bb = ld_f(bias, isf32, colc);
    float s = 0.f, s2 = 0.f;
    if (valid){
      size_t nb = (size_t)mt*16 + lq*4;         // C/D: row = quad*4 + reg
#pragma unroll
      for (int r = 0; r < 4; ++r){
        float val = acc[nt][r] + bb;
        hpre[(nb + r)*FD + colc] = f2bf(val);
        s += val; s2 += val*val;
      }
    }
    s  += __shfl_xor(s, 16);  s  += __shfl_xor(s, 32);
    s2 += __shfl_xor(s2, 16); s2 += __shfl_xor(s2, 32);
    if (lq == 0){
      atomicAdd(&red[colc], s);                 // LDS atomic
      atomicAdd(&red[128 + colc], s2);
    }
  }
  __syncthreads();
  bnpart[blockIdx.x*256 + tid] = red[tid];
}

// ---------------- BN finalize (16 blocks, shfl reduce) ----------------------

__global__ __launch_bounds__(256) void bn_final_kernel(const float* __restrict__ bnpart,
    const void* __restrict__ gamma, const void* __restrict__ beta,
    const void* __restrict__ Xraw, const void* __restrict__ eiraw,
    float* __restrict__ scale, float* __restrict__ shift)
{
  uint32 isf32, is64;
  get_flags((const uint32*)Xraw, (const uint32*)eiraw, isf32, is64);
  int tid = threadIdx.x;
  int f = blockIdx.x*8 + (tid >> 5);
  int l = tid & 31;
  float s = 0.f, q = 0.f;
  for (int b = l; b < GB2; b += 32){
    s += bnpart[b*256 + f];
    q += bnpart[b*256 + 128 + f];
  }
#pragma unroll
  for (int m = 16; m >= 1; m >>= 1){
    s += __shfl_xor(s, m);
    q += __shfl_xor(q, m);
  }
  if (l == 0){
    const float invN = 1.0f / (float)N_NODES;
    float mu  = s * invN;
    float var = q * invN - mu*mu;
    float scv = ld_f(gamma, isf32, f) * rsqrtf(var + 1e-5f);
    scale[f] = scv;
    shift[f] = ld_f(beta, isf32, f) - mu * scv;
  }
}

// ---------------- pool (BN2 + ReLU fused), high-occupancy -------------------

__global__ __launch_bounds__(256) void pool_partial_kernel(const ushort16* __restrict__ hp,
    const float* __restrict__ scale, const float* __restrict__ shift,
    const uint32* __restrict__ gstart, float* __restrict__ pool_part)
{
  __shared__ float wred[4*16*8];                 // 2 KB
  int tid = threadIdx.x;
  int g = blockIdx.x >> 5, chunk = blockIdx.x & 31;
  int slot = tid >> 4, l = tid & 15;
  int wave = tid >> 6, lane = tid & 63;
  uint32 st = gstart[g], cnt = gstart[g+1] - st;
  uint32 per = (cnt + PCH - 1) >> 5;
  uint32 b0 = st + chunk*per;
  uint32 b1 = b0 + per;
  uint32 e1 = st + cnt;
  if (b1 > e1) b1 = e1;
  float s0[8], h0[8], a[8];
#pragma unroll
  for (int j = 0; j < 8; ++j){ s0[j] = scale[l*8 + j]; h0[j] = shift[l*8 + j]; a[j] = 0.f; }
  for (uint32 n = b0 + slot; n < b1; n += 16){
    const uint4 v = *(const uint4*)(hp + (size_t)n*FD + l*8);
    float f[8];
    f[0] = bf2f_lo(v.x); f[1] = bf2f_hi(v.x);
    f[2] = bf2f_lo(v.y); f[3] = bf2f_hi(v.y);
    f[4] = bf2f_lo(v.z); f[5] = bf2f_hi(v.z);
    f[6] = bf2f_lo(v.w); f[7] = bf2f_hi(v.w);
#pragma unroll
    for (int j = 0; j < 8; ++j) a[j] += fmaxf(f[j]*s0[j] + h0[j], 0.f);
  }
#pragma unroll
  for (int j = 0; j < 8; ++j){
    a[j] += __shfl_xor(a[j], 16);
    a[j] += __shfl_xor(a[j], 32);
  }
  if (lane < 16){
#pragma unroll
    for (int j = 0; j < 8; ++j) wred[(wave*16 + lane)*8 + j] = a[j];
  }
  __syncthreads();
  if (tid < 16){
    float r[8];
#pragma unroll
    for (int j = 0; j < 8; ++j)
      r[j] = wred[(0*16 + tid)*8 + j] + wred[(1*16 + tid)*8 + j]
           + wred[(2*16 + tid)*8 + j] + wred[(3*16 + tid)*8 + j];
    float* dst = pool_part + (size_t)blockIdx.x*FD + tid*8;
#pragma unroll
    for (int j = 0; j < 8; ++j) dst[j] = r[j];
  }
}

__global__ void pool_final_kernel(const float* __restrict__ pool_part,
    const uint32* __restrict__ gstart, const void* __restrict__ Xraw,
    const void* __restrict__ eiraw, void* __restrict__ out)
{
  uint32 isf32, is64;
  get_flags((const uint32*)Xraw, (const uint32*)eiraw, isf32, is64);
  int t = blockIdx.x*256 + threadIdx.x;          // t < 8192
  int g = t >> 7, f = t & 127;
  float c = fmaxf((float)(gstart[g+1] - gstart[g]), 1.f);
  float v = 0.f;
#pragma unroll 8
  for (int ch = 0; ch < PCH; ++ch)
    v += pool_part[(size_t)(g*PCH + ch)*FD + f];
  v /= c;
  if (isf32) ((float*)out)[t] = v;
  else       ((ushort16*)out)[t] = f2bf(v);
}

// ---------------- launch ----------------

extern "C" void kernel_launch(void* const* d_in, const int* in_sizes, int n_in,
                              void* d_out, int out_size, void* d_ws, size_t ws_size,
                              hipStream_t stream)
{
  const void* x   = d_in[0];
  const void* ei  = d_in[1];
  const void* bat = d_in[2];
  const void* wl1 = d_in[3];
  const void* bl1 = d_in[4];
  const void* wr1 = d_in[5];
  const void* g1  = d_in[6];
  const void* be1 = d_in[7];
  const void* wl2 = d_in[8];
  const void* bl2 = d_in[9];
  const void* wr2 = d_in[10];
  const void* g2  = d_in[11];
  const void* be2 = d_in[12];
  char* ws = (char*)d_ws;

  // persistent
  uint32* gstart  = (uint32*)(ws + 64);           // 65 u32
  uint32* bbase   = (uint32*)(ws + 384);          // 197 u32
  float*  scale1  = (float*) (ws + 1280);
  float*  shift1  = (float*) (ws + 1792);
  float*  scale2  = (float*) (ws + 2304);
  float*  shift2  = (float*) (ws + 2816);
  uint32* rowstart= (uint32*)(ws + 3328);         // -> 203,328
  uint32* deg     = (uint32*)(ws + 203328);       // -> 403,328
  ushort16* colidx= (ushort16*)(ws + 403328);     // u16 -> 2,003,328
  uint32* part    = (uint32*)(ws + 2003328);      // 16*256 u32 -> 2,019,712
  uint32* pbase   = (uint32*)(ws + 2019712);      // 16*256 u32 -> 2,036,096
  short*  wfrag   = (short*) (ws + 2204032);      // 2 x 32768 shorts -> 2,335,104
  float*  bnpart  = (float*) (ws + 2335104);      // 782*256 f32 -> 3,135,872
  uint2*  z8      = (uint2*) (ws + 3135872);      // 6.4 MB -> 9,535,872
  uint2*  agg8    = (uint2*) (ws + 15935872);     // 6.4 MB -> 22,335,872
  ushort16* hp1   = (ushort16*)(ws + 28735872);   // 12.8 MB -> 41,535,872
  ushort16* hp2   = (ushort16*)(ws + 41535872);   // 12.8 MB -> 54,335,872
  // x8 (6.4 MB) aliases hp2's first half: last read (gemm1 A1) precedes
  // gemm2's hp2 write.
  uint2*  x8      = (uint2*) (ws + 41535872);
  // transient, inside hp1 (dead before gemm1 writes hp1):
  uint32* pack0   = (uint32*)(ws + 28735872);     // 3.2 MB
  uint32* pack1   = (uint32*)(ws + 31935872);     // 3.2 MB
  uint32* hist    = (uint32*)(ws + 35135872);     // 391*256 u32
  uint32* off     = (uint32*)(ws + 35536256);     // 391*256 u32
  // ppart overlaps pack0 region (pool runs after hp1's last read)
  float*  ppart   = (float*) (ws + 28735872);     // 2048*128 f32

  // CSR build + gseg + x->fp8 + wprep (one grid, no global atomics)
  pack_gseg_prep_kernel<<<GB + 196 + 3125 + 256, 256, 0, stream>>>(
      ei, bat, x, wl1, wr1, wl2, wr2, pack0, hist, gstart, x8, wfrag);
  scan_part_kernel <<<SBK, 256, 0, stream>>>(hist, part);
  scan_mid_kernel  <<<1,   256, 0, stream>>>(part, pbase, bbase);
  scan_off_kernel  <<<SBK, 256, 0, stream>>>(hist, pbase, off);
  scatter_kernel   <<<GB,  256, 0, stream>>>(pack0, off, pack1);
  bucket_csr_kernel<<<NBK, 256, 0, stream>>>(pack1, bbase, rowstart, deg, colidx);

  // layer 1 (fp8 gather of x8; gemm A0=agg8, A1=x8, both fp8)
  agg_kernel       <<<3125, 256, 0, stream>>>(x8, rowstart, deg, colidx, agg8);
  gemm_bn_kernel   <<<GB2,  256, 0, stream>>>(agg8, x8, ei, wfrag, bl1, x, hp1, bnpart);
  bn_final_kernel  <<<16,   256, 0, stream>>>(bnpart, g1, be1, x, ei, scale1, shift1);

  // layer 2 (z8 = fp8(relu(bn1(hp1))); gather z8; gemm A0=agg8, A1=z8)
  z8_kernel        <<<3125, 256, 0, stream>>>(hp1, scale1, shift1, z8);
  agg_kernel       <<<3125, 256, 0, stream>>>(z8, rowstart, deg, colidx, agg8);
  gemm_bn_kernel   <<<GB2,  256, 0, stream>>>(agg8, z8, ei, wfrag + 32768, bl2, x, hp2, bnpart);
  bn_final_kernel  <<<16,   256, 0, stream>>>(bnpart, g2, be2, x, ei, scale2, shift2);

  // pool (BN2 + ReLU fused)
  pool_partial_kernel<<<NGRAPH*PCH, 256, 0, stream>>>(hp2, scale2, shift2, gstart, ppart);
  pool_final_kernel  <<<32,  256, 0, stream>>>(ppart, gstart, x, ei, d_out);
}